// Round 12
// baseline (197.087 us; speedup 1.0000x reference)
//
#include <hip/hip_runtime.h>
#include <math.h>

// Problem: B=64, R=20, L=1024, D=2048 fp32.  out[b,l] = max_r <region[b,r,:], word[b,l,:]>
// Memory-bound: 548 MB mandatory -> ~84us @ 6.6TB/s measured-achievable.
//
// Round-12 = round-11 (MFMA, 114us) + 4-deep word prefetch.
//  - round-11 proved the MFMA restructure: acc = 8 VGPR (vs 80 scalar), so
//    prefetch depth is finally affordable without crossing the 128-VGPR
//    cliff (rounds 6/9 regression cause).
//  - words prefetched 4 K-steps ahead in 4 named float4 reg groups (A-D);
//    steady-state wait = vmcnt(6): 3 groups (96B/lane, 96KB/CU) in flight.
//  - regions -> bf16 A-fragments staged ONCE in LDS (80 KB, ONE barrier).
//  - M=20 = rows 0-15 tile + rows 16-19 replicated 4x (dups harmless in max).
//  - 512 thr / 8 waves, 16 words/wave, 128 words/block, grid 512, 2 blocks/CU.
#define NREG   20
#define LWORDS 1024
#define DDIM   2048
#define TPB    512
#define KSTEPS (DDIM / 32)          // 64 MFMA K-steps

typedef __attribute__((ext_vector_type(8))) short bf16x8;
typedef __attribute__((ext_vector_type(4))) float f32x4;

// fp32 -> bf16 round-to-nearest-even (inputs finite)
__device__ __forceinline__ ushort f2bf(float f) {
    union { float f; unsigned u; } v; v.f = f;
    const unsigned u = v.u;
    return (ushort)((u + 0x7fffu + ((u >> 16) & 1u)) >> 16);
}

#define CVT8(bq, p0, p1)                                                       \
    do {                                                                       \
        bq[0] = (short)f2bf(p0.x); bq[1] = (short)f2bf(p0.y);                  \
        bq[2] = (short)f2bf(p0.z); bq[3] = (short)f2bf(p0.w);                  \
        bq[4] = (short)f2bf(p1.x); bq[5] = (short)f2bf(p1.y);                  \
        bq[6] = (short)f2bf(p1.z); bq[7] = (short)f2bf(p1.w);                  \
    } while (0)

// load one K-step's 32B (2 x float4) for this lane; guarded reload of 0 on tail
#define WLOAD(va, vb, ks_expr)                                                 \
    do {                                                                       \
        const int kk_ = (ks_expr);                                             \
        const size_t off_ = (kk_ < KSTEPS) ? (size_t)kk_ * 32 : 0;             \
        const float* p_ = wbase + off_;                                        \
        va = *reinterpret_cast<const float4*>(p_);                             \
        vb = *reinterpret_cast<const float4*>(p_ + 4);                         \
    } while (0)

// one MFMA K-step: cvt word regs -> bf16, read A-fragments, 2 MFMAs
#define CSTEP(ks_expr, va, vb)                                                 \
    do {                                                                       \
        const int kk_ = (ks_expr);                                             \
        bf16x8 bq_; CVT8(bq_, va, vb);                                         \
        const bf16x8 a0_ = lds0[kk_ * 64 + lane];                              \
        const bf16x8 a1_ = lds1[kk_ * 16 + (col & 3) * 4 + kg];                \
        acc0 = __builtin_amdgcn_mfma_f32_16x16x32_bf16(a0_, bq_, acc0, 0, 0, 0); \
        acc1 = __builtin_amdgcn_mfma_f32_16x16x32_bf16(a1_, bq_, acc1, 0, 0, 0); \
    } while (0)

__global__ __launch_bounds__(TPB)
void score_mfma_kernel(const float* __restrict__ in0,   // (B*20, D) regions
                       const float* __restrict__ in1,   // (B, L, D) words
                       float* __restrict__ out) {       // (B, 1, L)
    // A-fragments, lane-sequential 16B reads (conflict-free):
    //  lds0[ks*64 + lane]          : rows 0-15,  row=lane&15, k=ks*32+(lane>>4)*8
    //  lds1[ks*16 + (row&3)*4 + kg]: rows 16-19 compact (4-lane broadcast read)
    __shared__ bf16x8 lds0[KSTEPS * 64];   // 64 KB
    __shared__ bf16x8 lds1[KSTEPS * 16];   // 16 KB

    const int bid  = blockIdx.x;
    const int b    = bid & 63;              // batch -> XCD b%8
    const int tb   = bid >> 6;              // word slab 0..7 (128 words each)
    const int tid  = threadIdx.x;
    const int wave = tid >> 6;
    const int lane = tid & 63;
    const int col  = lane & 15;             // word column within 16-word tile
    const int kg   = lane >> 4;             // k-group 0..3 (8 k each)

    const float* reg0 = in0 + (size_t)b * NREG * DDIM;

    // ---- stage regions once: fp32 -> bf16 -> fragment-ordered LDS ----
    #pragma unroll
    for (int i = 0; i < 8; ++i) {           // rows 0-15: 4096 slots
        const int S = i * TPB + tid;
        const int ks = S >> 6, l = S & 63, r = l & 15, g = l >> 4;
        const float* src = reg0 + (size_t)r * DDIM + ks * 32 + g * 8;
        const float4 x = *reinterpret_cast<const float4*>(src);
        const float4 y = *reinterpret_cast<const float4*>(src + 4);
        bf16x8 o; CVT8(o, x, y);
        lds0[S] = o;
    }
    #pragma unroll
    for (int i = 0; i < 2; ++i) {           // rows 16-19: 1024 slots
        const int S = i * TPB + tid;
        const int ks = S >> 4, r4 = (S >> 2) & 3, g = S & 3;
        const float* src = reg0 + (size_t)(16 + r4) * DDIM + ks * 32 + g * 8;
        const float4 x = *reinterpret_cast<const float4*>(src);
        const float4 y = *reinterpret_cast<const float4*>(src + 4);
        bf16x8 o; CVT8(o, x, y);
        lds1[S] = o;
    }
    __syncthreads();   // the ONLY barrier in the kernel

    // ---- stream words as B-fragments straight from global ----
    const float* wbase = in1
        + ((size_t)b * LWORDS + tb * 128 + wave * 16 + col) * DDIM + kg * 8;

    f32x4 acc0 = {0.f, 0.f, 0.f, 0.f};      // rows 0-15
    f32x4 acc1 = {0.f, 0.f, 0.f, 0.f};      // rows 16-19 (x4 duplicated)

    // 4-deep pipeline in named reg groups (rule #20: no arrays, no pointers)
    float4 Aa, Ab, Ba, Bb, Ca, Cb, Da, Db;
    WLOAD(Aa, Ab, 0);
    WLOAD(Ba, Bb, 1);
    WLOAD(Ca, Cb, 2);
    WLOAD(Da, Db, 3);

    for (int ks = 0; ks < KSTEPS; ks += 4) {
        CSTEP(ks + 0, Aa, Ab);  WLOAD(Aa, Ab, ks + 4);
        CSTEP(ks + 1, Ba, Bb);  WLOAD(Ba, Bb, ks + 5);
        CSTEP(ks + 2, Ca, Cb);  WLOAD(Ca, Cb, ks + 6);
        CSTEP(ks + 3, Da, Db);  WLOAD(Da, Db, ks + 7);
    }

    // ---- max over regions ----
    // D layout (m89-verified): col = lane&15, row = (lane>>4)*4 + reg.
    float m = fmaxf(fmaxf(fmaxf(acc0[0], acc0[1]), fmaxf(acc0[2], acc0[3])),
                    fmaxf(fmaxf(acc1[0], acc1[1]), fmaxf(acc1[2], acc1[3])));
    m = fmaxf(m, __shfl_xor(m, 16, 64));
    m = fmaxf(m, __shfl_xor(m, 32, 64));
    if (lane < 16)
        out[(size_t)b * LWORDS + tb * 128 + wave * 16 + col] = m;
}

extern "C" void kernel_launch(void* const* d_in, const int* in_sizes, int n_in,
                              void* d_out, int out_size, void* d_ws, size_t ws_size,
                              hipStream_t stream) {
    const float* in0 = (const float*)d_in[0];   // (B*20, D)
    const float* in1 = (const float*)d_in[1];   // (B, L, D)
    float* out = (float*)d_out;                  // (B, 1, L)

    const int grid = 64 * (LWORDS / 128);        // 512 blocks, 2/CU (80KB LDS)
    score_mfma_kernel<<<grid, TPB, 0, stream>>>(in0, in1, out);
}

// Round 13
// 119.305 us; speedup vs baseline: 1.6520x; 1.6520x over previous
//
#include <hip/hip_runtime.h>
#include <math.h>

// Problem: B=64, R=20, L=1024, D=2048 fp32.  out[b,l] = max_r <region[b,r,:], word[b,l,:]>
// Memory-bound: 548 MB mandatory -> ~84us @ 6.6TB/s measured-achievable.
//
// Round-13 = round-11 MFMA structure + K-SPLIT ACROSS WAVE PAIRS (2x occupancy).
//  - Wave cap was the latency-hiding limit: 65536 words / 16 per wave = 4096
//    waves = 4 waves/SIMD. Deeper per-wave prefetch crosses the 128-VGPR
//    cliff (rounds 6/9/12). Instead: TPB=1024, waves 0-7 do K[0,1024),
//    waves 8-15 do K[1024,2048) for the SAME 128 words; partials summed via
//    LDS at the end (max doesn't distribute over the K-sum).
//  - 2 blocks/CU x 16 waves = 32 waves/CU = 8/SIMD, needs VGPR <= 64:
//    enforced by __launch_bounds__(1024, 8). Affordable ONLY because the
//    MFMA acc is 8 VGPR (the scalar kernel's 80-reg acc made any cap fatal).
//  - LDS 80 KB x 2 blocks = 160 KB exact; threads 2048 exact.
//  - regions staged ONCE as bf16 fragments (one barrier); words stream from
//    global, 2-deep ping-pong in named regs, guard-free via peeled tail.
#define NREG   20
#define LWORDS 1024
#define DDIM   2048
#define TPB    1024
#define KSTEPS 64                   // total MFMA K-steps (K=32 each)
#define KHALF  32                   // K-steps per wave (half)

typedef __attribute__((ext_vector_type(8))) short bf16x8;
typedef __attribute__((ext_vector_type(4))) float f32x4;

// fp32 -> bf16 round-to-nearest-even (inputs finite)
__device__ __forceinline__ ushort f2bf(float f) {
    union { float f; unsigned u; } v; v.f = f;
    const unsigned u = v.u;
    return (ushort)((u + 0x7fffu + ((u >> 16) & 1u)) >> 16);
}

#define CVT8(bq, p0, p1)                                                       \
    do {                                                                       \
        bq[0] = (short)f2bf(p0.x); bq[1] = (short)f2bf(p0.y);                  \
        bq[2] = (short)f2bf(p0.z); bq[3] = (short)f2bf(p0.w);                  \
        bq[4] = (short)f2bf(p1.x); bq[5] = (short)f2bf(p1.y);                  \
        bq[6] = (short)f2bf(p1.z); bq[7] = (short)f2bf(p1.w);                  \
    } while (0)

// unguarded: callers guarantee kk < KHALF
#define WLOAD(va, vb, kk)                                                      \
    do {                                                                       \
        const float* p_ = wbase + (size_t)(kk) * 32;                           \
        va = *reinterpret_cast<const float4*>(p_);                             \
        vb = *reinterpret_cast<const float4*>(p_ + 4);                         \
    } while (0)

// one MFMA K-step at local step kk (fragment index h*KHALF + kk)
#define CSTEP(kk, va, vb)                                                      \
    do {                                                                       \
        const int kg_ = (h * KHALF + (kk));                                    \
        bf16x8 bq_; CVT8(bq_, va, vb);                                         \
        const bf16x8 a0_ = lds0[kg_ * 64 + lane];                              \
        const bf16x8 a1_ = lds1[kg_ * 16 + (col & 3) * 4 + kg];                \
        acc0 = __builtin_amdgcn_mfma_f32_16x16x32_bf16(a0_, bq_, acc0, 0, 0, 0); \
        acc1 = __builtin_amdgcn_mfma_f32_16x16x32_bf16(a1_, bq_, acc1, 0, 0, 0); \
    } while (0)

__global__ __launch_bounds__(TPB, 8)   // 8 waves/EU -> 2 blocks/CU, VGPR cap 64
void score_mfma_kernel(const float* __restrict__ in0,   // (B*20, D) regions
                       const float* __restrict__ in1,   // (B, L, D) words
                       float* __restrict__ out) {       // (B, 1, L)
    // A-fragments, lane-sequential 16B reads (conflict-free):
    //  lds0[ks*64 + lane]          : rows 0-15,  row=lane&15, k=ks*32+(lane>>4)*8
    //  lds1[ks*16 + (row&3)*4 + kg]: rows 16-19 compact (4-lane broadcast read)
    __shared__ bf16x8 lds0[KSTEPS * 64];   // 64 KB
    __shared__ bf16x8 lds1[KSTEPS * 16];   // 16 KB

    const int bid  = blockIdx.x;
    const int b    = bid & 63;              // batch -> XCD b%8
    const int tb   = bid >> 6;              // word slab 0..7 (128 words each)
    const int tid  = threadIdx.x;
    const int wave = tid >> 6;
    const int lane = tid & 63;
    const int col  = lane & 15;             // word column within 16-word tile
    const int kg   = lane >> 4;             // k-group 0..3 (8 k each)
    const int p    = wave & 7;              // word-tile pair id 0..7
    const int h    = wave >> 3;             // K-half 0/1

    const float* reg0 = in0 + (size_t)b * NREG * DDIM;

    // ---- stage regions once: fp32 -> bf16 -> fragment-ordered LDS ----
    #pragma unroll
    for (int i = 0; i < 4; ++i) {           // rows 0-15: 4096 slots
        const int S = i * TPB + tid;
        const int ks = S >> 6, l = S & 63, r = l & 15, g = l >> 4;
        const float* src = reg0 + (size_t)r * DDIM + ks * 32 + g * 8;
        const float4 x = *reinterpret_cast<const float4*>(src);
        const float4 y = *reinterpret_cast<const float4*>(src + 4);
        bf16x8 o; CVT8(o, x, y);
        lds0[S] = o;
    }
    {                                        // rows 16-19: 1024 slots
        const int S = tid;
        const int ks = S >> 4, r4 = (S >> 2) & 3, g = S & 3;
        const float* src = reg0 + (size_t)(16 + r4) * DDIM + ks * 32 + g * 8;
        const float4 x = *reinterpret_cast<const float4*>(src);
        const float4 y = *reinterpret_cast<const float4*>(src + 4);
        bf16x8 o; CVT8(o, x, y);
        lds1[S] = o;
    }
    __syncthreads();

    // ---- stream words: wave (p,h) does words p*16.. of slab, K-half h ----
    const float* wbase = in1
        + ((size_t)b * LWORDS + tb * 128 + p * 16 + col) * DDIM
        + (size_t)h * (KHALF * 32) + kg * 8;

    f32x4 acc0 = {0.f, 0.f, 0.f, 0.f};      // rows 0-15
    f32x4 acc1 = {0.f, 0.f, 0.f, 0.f};      // rows 16-19 (x4 duplicated)

    float4 pa0, pa1, pb0, pb1;
    WLOAD(pa0, pa1, 0);
    WLOAD(pb0, pb1, 1);

    for (int ks = 0; ks < KHALF - 2; ks += 2) {
        CSTEP(ks,     pa0, pa1);  WLOAD(pa0, pa1, ks + 2);
        CSTEP(ks + 1, pb0, pb1);  WLOAD(pb0, pb1, ks + 3);
    }
    CSTEP(KHALF - 2, pa0, pa1);             // peeled tail, no loads, no guards
    CSTEP(KHALF - 1, pb0, pb1);

    // ---- combine K-halves: waves 8-15 pass partials to waves 0-7 via LDS ----
    float* xbuf = reinterpret_cast<float*>(lds0);   // reuse region LDS (16 KB)
    __syncthreads();   // ALL waves done with lds0/lds1 reads
    if (wave >= 8) {
        float* dst = xbuf + ((size_t)(wave - 8) * 64 + lane) * 8;
        *reinterpret_cast<f32x4*>(dst)     = acc0;
        *reinterpret_cast<f32x4*>(dst + 4) = acc1;
    }
    __syncthreads();
    if (wave < 8) {
        const float* src = xbuf + ((size_t)wave * 64 + lane) * 8;
        const f32x4 o0 = *reinterpret_cast<const f32x4*>(src);
        const f32x4 o1 = *reinterpret_cast<const f32x4*>(src + 4);
        acc0 += o0;
        acc1 += o1;

        // D layout (m89-verified): col = lane&15, row = (lane>>4)*4 + reg.
        float m = fmaxf(fmaxf(fmaxf(acc0[0], acc0[1]), fmaxf(acc0[2], acc0[3])),
                        fmaxf(fmaxf(acc1[0], acc1[1]), fmaxf(acc1[2], acc1[3])));
        m = fmaxf(m, __shfl_xor(m, 16, 64));
        m = fmaxf(m, __shfl_xor(m, 32, 64));
        if (lane < 16)
            out[(size_t)b * LWORDS + tb * 128 + p * 16 + col] = m;
    }
}

extern "C" void kernel_launch(void* const* d_in, const int* in_sizes, int n_in,
                              void* d_out, int out_size, void* d_ws, size_t ws_size,
                              hipStream_t stream) {
    const float* in0 = (const float*)d_in[0];   // (B*20, D)
    const float* in1 = (const float*)d_in[1];   // (B, L, D)
    float* out = (float*)d_out;                  // (B, 1, L)

    const int grid = 64 * (LWORDS / 128);        // 512 blocks, 2/CU, 32 waves/CU
    score_mfma_kernel<<<grid, TPB, 0, stream>>>(in0, in1, out);
}

// Round 15
// 110.737 us; speedup vs baseline: 1.7798x; 1.0774x over previous
//
#include <hip/hip_runtime.h>
#include <hip/hip_bf16.h>
#include <math.h>
#include <string.h>

// Problem: B=64, R=20, L=1024, D=2048 fp32.  out[b,l] = max_r <region[b,r,:], word[b,l,:]>
// Memory-bound: 548 MB mandatory -> ~84-98us @ measured achievable BW.
//
// Round-15 = round-14 with the bit_cast compile error fixed (memcpy punning;
// __hip_bfloat162 is not trivially copyable so __builtin_bit_cast rejects it).
//  - round-13 falsified occupancy as the limiter (8 waves/SIMD == 4 w/SIMD).
//  - suspect under test: inner-loop fp32->bf16 bit-twiddle = ~32 VALU instrs
//    per K-step on the load->MFMA critical path. v_cvt_pk_bf16_f32 via
//    __float22bfloat162_rn cuts it to ~4.
//  - word prefetch: 2-deep ping-pong in named regs (rounds 6/9/12: deeper
//    crosses the 128-VGPR cliff at TPB=512/2 blocks/CU). Guards removed via
//    peeled tail; first loads issued BEFORE staging (stream starts at t=0).
//  - regions staged ONCE as bf16 A-fragments in 80 KB LDS, ONE barrier.
//  - M=20 = rows 0-15 + rows 16-19 replicated 4x (dups harmless under max).
#define NREG   20
#define LWORDS 1024
#define DDIM   2048
#define TPB    512
#define KSTEPS (DDIM / 32)          // 64 MFMA K-steps

typedef __attribute__((ext_vector_type(8))) short bf16x8;
typedef __attribute__((ext_vector_type(4))) float f32x4;
typedef __attribute__((ext_vector_type(4))) unsigned int u32x4;

// pack 2 fp32 -> 2 bf16 (RNE) -> one u32; compiler emits v_cvt_pk_bf16_f32
__device__ __forceinline__ unsigned pk2(float lo, float hi) {
    __hip_bfloat162 h = __float22bfloat162_rn(make_float2(lo, hi));
    unsigned u;
    memcpy(&u, &h, 4);
    return u;
}

#define CVT8(bq, p0, p1)                                                       \
    do {                                                                       \
        u32x4 t_;                                                              \
        t_[0] = pk2(p0.x, p0.y); t_[1] = pk2(p0.z, p0.w);                      \
        t_[2] = pk2(p1.x, p1.y); t_[3] = pk2(p1.z, p1.w);                      \
        memcpy(&bq, &t_, 16);                                                  \
    } while (0)

// unguarded: callers guarantee kk < KSTEPS
#define WLOAD(va, vb, kk)                                                      \
    do {                                                                       \
        const float* p_ = wbase + (size_t)(kk) * 32;                           \
        va = *reinterpret_cast<const float4*>(p_);                             \
        vb = *reinterpret_cast<const float4*>(p_ + 4);                         \
    } while (0)

// one MFMA K-step: cvt word regs -> bf16, read A-fragments, 2 MFMAs
#define CSTEP(kk, va, vb)                                                      \
    do {                                                                       \
        bf16x8 bq_; CVT8(bq_, va, vb);                                         \
        const bf16x8 a0_ = lds0[(kk) * 64 + lane];                             \
        const bf16x8 a1_ = lds1[(kk) * 16 + (col & 3) * 4 + kg];               \
        acc0 = __builtin_amdgcn_mfma_f32_16x16x32_bf16(a0_, bq_, acc0, 0, 0, 0); \
        acc1 = __builtin_amdgcn_mfma_f32_16x16x32_bf16(a1_, bq_, acc1, 0, 0, 0); \
    } while (0)

__global__ __launch_bounds__(TPB)
void score_mfma_kernel(const float* __restrict__ in0,   // (B*20, D) regions
                       const float* __restrict__ in1,   // (B, L, D) words
                       float* __restrict__ out) {       // (B, 1, L)
    // A-fragments, lane-sequential 16B reads (conflict-free):
    //  lds0[ks*64 + lane]          : rows 0-15,  row=lane&15, k=ks*32+(lane>>4)*8
    //  lds1[ks*16 + (row&3)*4 + kg]: rows 16-19 compact (4-lane broadcast read)
    __shared__ bf16x8 lds0[KSTEPS * 64];   // 64 KB
    __shared__ bf16x8 lds1[KSTEPS * 16];   // 16 KB

    const int bid  = blockIdx.x;
    const int b    = bid & 63;              // batch -> XCD b%8
    const int tb   = bid >> 6;              // word slab 0..7 (128 words each)
    const int tid  = threadIdx.x;
    const int wave = tid >> 6;
    const int lane = tid & 63;
    const int col  = lane & 15;             // word column within 16-word tile
    const int kg   = lane >> 4;             // k-group 0..3 (8 k each)

    const float* reg0 = in0 + (size_t)b * NREG * DDIM;
    const float* wbase = in1
        + ((size_t)b * LWORDS + tb * 128 + wave * 16 + col) * DDIM + kg * 8;

    // pre-issue the first two word prefetches: word stream starts at t=0,
    // overlapping the staging phase below.
    float4 pa0, pa1, pb0, pb1;
    WLOAD(pa0, pa1, 0);
    WLOAD(pb0, pb1, 1);

    // ---- stage regions once: fp32 -> bf16 -> fragment-ordered LDS ----
    #pragma unroll
    for (int i = 0; i < 8; ++i) {           // rows 0-15: 4096 slots
        const int S = i * TPB + tid;
        const int ks = S >> 6, l = S & 63, r = l & 15, g = l >> 4;
        const float* src = reg0 + (size_t)r * DDIM + ks * 32 + g * 8;
        const float4 x = *reinterpret_cast<const float4*>(src);
        const float4 y = *reinterpret_cast<const float4*>(src + 4);
        bf16x8 o; CVT8(o, x, y);
        lds0[S] = o;
    }
    #pragma unroll
    for (int i = 0; i < 2; ++i) {           // rows 16-19: 1024 slots
        const int S = i * TPB + tid;
        const int ks = S >> 4, r4 = (S >> 2) & 3, g = S & 3;
        const float* src = reg0 + (size_t)(16 + r4) * DDIM + ks * 32 + g * 8;
        const float4 x = *reinterpret_cast<const float4*>(src);
        const float4 y = *reinterpret_cast<const float4*>(src + 4);
        bf16x8 o; CVT8(o, x, y);
        lds1[S] = o;
    }
    __syncthreads();   // the ONLY barrier in the kernel

    f32x4 acc0 = {0.f, 0.f, 0.f, 0.f};      // rows 0-15
    f32x4 acc1 = {0.f, 0.f, 0.f, 0.f};      // rows 16-19 (x4 duplicated)

    for (int ks = 0; ks < KSTEPS - 2; ks += 2) {
        CSTEP(ks,     pa0, pa1);  WLOAD(pa0, pa1, ks + 2);
        CSTEP(ks + 1, pb0, pb1);  WLOAD(pb0, pb1, ks + 3);
    }
    CSTEP(KSTEPS - 2, pa0, pa1);            // peeled tail: no loads, no guards
    CSTEP(KSTEPS - 1, pb0, pb1);

    // ---- max over regions ----
    // D layout (m89-verified): col = lane&15, row = (lane>>4)*4 + reg.
    float m = fmaxf(fmaxf(fmaxf(acc0[0], acc0[1]), fmaxf(acc0[2], acc0[3])),
                    fmaxf(fmaxf(acc1[0], acc1[1]), fmaxf(acc1[2], acc1[3])));
    m = fmaxf(m, __shfl_xor(m, 16, 64));
    m = fmaxf(m, __shfl_xor(m, 32, 64));
    if (lane < 16)
        out[(size_t)b * LWORDS + tb * 128 + wave * 16 + col] = m;
}

extern "C" void kernel_launch(void* const* d_in, const int* in_sizes, int n_in,
                              void* d_out, int out_size, void* d_ws, size_t ws_size,
                              hipStream_t stream) {
    const float* in0 = (const float*)d_in[0];   // (B*20, D)
    const float* in1 = (const float*)d_in[1];   // (B, L, D)
    float* out = (float*)d_out;                  // (B, 1, L)

    const int grid = 64 * (LWORDS / 128);        // 512 blocks, 2/CU (80KB LDS)
    score_mfma_kernel<<<grid, TPB, 0, stream>>>(in0, in1, out);
}